// Round 2
// baseline (244.029 us; speedup 1.0000x reference)
//
#include <hip/hip_runtime.h>
#include <hip/hip_bf16.h>
#include <math.h>

#define BSZ 4096
#define DSZ 1024

typedef __attribute__((ext_vector_type(8))) short bf16x8;   // 8 bf16 = 4 VGPRs
typedef __attribute__((ext_vector_type(4))) float f32x4;    // mfma 16x16 accum

__device__ inline unsigned short f2bf_rne(float f) {
    unsigned int u = __float_as_uint(f);
    u += 0x7fffu + ((u >> 16) & 1u);      // round-to-nearest-even
    return (unsigned short)(u >> 16);
}

// ---------------------------------------------------------------------------
// Kernel 1: fp32 -> bf16 conversion + exact fp32 row squared-norms.
// grid = (4096, 2): y==0 -> image, y==1 -> text. One block (256 thr) per row.
// ---------------------------------------------------------------------------
__global__ __launch_bounds__(256) void cvt_norm_kernel(
        const float* __restrict__ img, const float* __restrict__ txt,
        unsigned short* __restrict__ imgb, unsigned short* __restrict__ txtb,
        float* __restrict__ img_sq, float* __restrict__ txt_sq) {
    const int row = blockIdx.x;
    const bool isTxt = (blockIdx.y != 0);
    const float* __restrict__ src = isTxt ? txt : img;
    unsigned short* __restrict__ dst = isTxt ? txtb : imgb;
    float* __restrict__ sq = isTxt ? txt_sq : img_sq;

    const int t = threadIdx.x;                       // 256 thr * float4 = 1024
    const float4 v = reinterpret_cast<const float4*>(src + (size_t)row * DSZ)[t];

    ushort4 o;
    o.x = f2bf_rne(v.x); o.y = f2bf_rne(v.y);
    o.z = f2bf_rne(v.z); o.w = f2bf_rne(v.w);
    reinterpret_cast<ushort4*>(dst + (size_t)row * DSZ)[t] = o;

    float s = v.x * v.x + v.y * v.y + v.z * v.z + v.w * v.w;
    #pragma unroll
    for (int off = 32; off; off >>= 1) s += __shfl_down(s, off);

    __shared__ float lds[4];
    if ((t & 63) == 0) lds[t >> 6] = s;
    __syncthreads();
    if (t == 0) sq[row] = lds[0] + lds[1] + lds[2] + lds[3];
}

// ---------------------------------------------------------------------------
// Kernel 2: bf16 MFMA cross-GEMM (img @ txt^T) fused with dist/exp/row-sum.
// 128x128 tile per block, 4 waves in 2x2; each wave: 4x4 frags of 16x16x32.
// Fragments loaded directly from global bf16 (L1/L2-resident working set).
//   A-frag (img): lane holds row (lane&15), k-chunk (lane>>4)*8, contiguous.
//   B-frag (txt): lane holds col (lane&15) = text row, same k layout.
//   C/D: col = lane&15, row = (lane>>4)*4 + j   [verified m89]
// ---------------------------------------------------------------------------
__global__ __launch_bounds__(256) void fused_mfma_kernel(
        const unsigned short* __restrict__ imgb,
        const unsigned short* __restrict__ txtb,
        const float* __restrict__ img_sq, const float* __restrict__ txt_sq,
        float* __restrict__ rowsum, float* __restrict__ diag_dist) {

    const int bi = blockIdx.y;               // image tile
    const int bj = blockIdx.x;               // text tile
    const int tid  = threadIdx.x;
    const int lane = tid & 63;
    const int w    = tid >> 6;               // wave 0..3
    const int wy   = w >> 1, wx = w & 1;
    const int lr   = lane >> 4;              // 0..3
    const int lc   = lane & 15;              // 0..15

    const int ib = bi * 128 + wy * 64;       // wave's first image row
    const int jb = bj * 128 + wx * 64;       // wave's first text row

    const unsigned short* __restrict__ pA = imgb + (size_t)(ib + lc) * DSZ + lr * 8;
    const unsigned short* __restrict__ pB = txtb + (size_t)(jb + lc) * DSZ + lr * 8;

    f32x4 acc[4][4] = {};

    for (int k0 = 0; k0 < DSZ; k0 += 32) {
        bf16x8 a[4], b[4];
        #pragma unroll
        for (int m = 0; m < 4; ++m)
            a[m] = *reinterpret_cast<const bf16x8*>(pA + (size_t)m * 16 * DSZ + k0);
        #pragma unroll
        for (int n = 0; n < 4; ++n)
            b[n] = *reinterpret_cast<const bf16x8*>(pB + (size_t)n * 16 * DSZ + k0);
        #pragma unroll
        for (int m = 0; m < 4; ++m)
            #pragma unroll
            for (int n = 0; n < 4; ++n)
                acc[m][n] = __builtin_amdgcn_mfma_f32_16x16x32_bf16(
                                a[m], b[n], acc[m][n], 0, 0, 0);
    }

    // ---- epilogue: dist -> sim -> row partial sums + diagonal ----
    float tq[4];
    #pragma unroll
    for (int n = 0; n < 4; ++n) tq[n] = txt_sq[jb + n * 16 + lc];

    float rs[4][4];                           // [m][j] row partial sums
    #pragma unroll
    for (int m = 0; m < 4; ++m) {
        #pragma unroll
        for (int j = 0; j < 4; ++j) {
            const int gi = ib + m * 16 + lr * 4 + j;
            const float iqv = img_sq[gi];
            float s = 0.0f;
            #pragma unroll
            for (int n = 0; n < 4; ++n) {
                const float d2 = iqv + tq[n] - 2.0f * acc[m][n][j];
                const float d  = sqrtf(fmaxf(d2, 0.0f));
                const float sim = __expf(-20.0f * d);
                s += sim;
                const int gj = jb + n * 16 + lc;
                if (gi == gj) diag_dist[gi] = d;
            }
            rs[m][j] = s;
        }
    }

    // butterfly across the 16 lanes of each lr-group, then 1 atomic per row
    #pragma unroll
    for (int off = 1; off < 16; off <<= 1)
        #pragma unroll
        for (int m = 0; m < 4; ++m)
            #pragma unroll
            for (int j = 0; j < 4; ++j)
                rs[m][j] += __shfl_xor(rs[m][j], off);

    if (lc == 0) {
        #pragma unroll
        for (int m = 0; m < 4; ++m)
            #pragma unroll
            for (int j = 0; j < 4; ++j)
                atomicAdd(&rowsum[ib + m * 16 + lr * 4 + j], rs[m][j]);
    }
}

// ---------------------------------------------------------------------------
// Kernel 3: per_sample = d_ii/T + log(rowsum_i - exp(-d_ii/T)); mean over i.
// ---------------------------------------------------------------------------
__global__ __launch_bounds__(256) void finalize_kernel(
        const float* __restrict__ rowsum, const float* __restrict__ diag_dist,
        float* __restrict__ out) {
    const int tid = threadIdx.x;
    float s = 0.0f;
    for (int i = tid; i < BSZ; i += 256) {
        const float d   = diag_dist[i];
        const float num = __expf(-20.0f * d);
        const float den = rowsum[i] - num;
        s += (den != 0.0f) ? (20.0f * d + logf(den)) : 0.0f;
    }
    #pragma unroll
    for (int off = 32; off; off >>= 1) s += __shfl_down(s, off);

    __shared__ float lds[4];
    if ((tid & 63) == 0) lds[tid >> 6] = s;
    __syncthreads();
    if (tid == 0) out[0] = (lds[0] + lds[1] + lds[2] + lds[3]) * (1.0f / (float)BSZ);
}

// ---------------------------------------------------------------------------
extern "C" void kernel_launch(void* const* d_in, const int* in_sizes, int n_in,
                              void* d_out, int out_size, void* d_ws, size_t ws_size,
                              hipStream_t stream) {
    // setup_inputs() order: text_embeddings first, image_embeddings second.
    const float* txt = (const float*)d_in[0];
    const float* img = (const float*)d_in[1];
    float* out = (float*)d_out;

    // workspace layout: bf16 copies (8 MB each) then fp32 scalars
    unsigned short* imgb = (unsigned short*)d_ws;
    unsigned short* txtb = imgb + (size_t)BSZ * DSZ;
    float* fws     = (float*)(txtb + (size_t)BSZ * DSZ);
    float* rowsum  = fws;             // [4096] zero-init below
    float* diag    = fws + BSZ;       // [4096]
    float* img_sq  = fws + 2 * BSZ;   // [4096]
    float* txt_sq  = fws + 3 * BSZ;   // [4096]

    hipMemsetAsync(rowsum, 0, BSZ * sizeof(float), stream);

    cvt_norm_kernel<<<dim3(BSZ, 2), 256, 0, stream>>>(img, txt, imgb, txtb,
                                                      img_sq, txt_sq);

    fused_mfma_kernel<<<dim3(BSZ / 128, BSZ / 128), 256, 0, stream>>>(
        imgb, txtb, img_sq, txt_sq, rowsum, diag);

    finalize_kernel<<<1, 256, 0, stream>>>(rowsum, diag, out);
}

// Round 3
// 153.412 us; speedup vs baseline: 1.5907x; 1.5907x over previous
//
#include <hip/hip_runtime.h>
#include <hip/hip_bf16.h>
#include <math.h>

#define BSZ 4096
#define DSZ 1024
#define BK  32
#define NT  (DSZ / BK)   // 32 k-steps

typedef unsigned short ushort_t;
typedef __attribute__((ext_vector_type(8))) short bf16x8;   // 8 bf16 = 4 VGPRs
typedef __attribute__((ext_vector_type(4))) float f32x4;    // mfma 16x16 accum

__device__ inline ushort_t f2bf_rne(float f) {
    unsigned int u = __float_as_uint(f);
    u += 0x7fffu + ((u >> 16) & 1u);      // round-to-nearest-even
    return (ushort_t)(u >> 16);
}

// ---------------------------------------------------------------------------
// Kernel 1: fp32 -> bf16 conversion + exact fp32 row squared-norms.
// Also zeroes rowsum[] (ws is poisoned 0xAA before every launch).
// grid = (4096, 2): y==0 -> image, y==1 -> text. One block (256 thr) per row.
// ---------------------------------------------------------------------------
__global__ __launch_bounds__(256) void cvt_norm_kernel(
        const float* __restrict__ img, const float* __restrict__ txt,
        ushort_t* __restrict__ imgb, ushort_t* __restrict__ txtb,
        float* __restrict__ img_sq, float* __restrict__ txt_sq,
        float* __restrict__ rowsum) {
    const int row = blockIdx.x;
    const bool isTxt = (blockIdx.y != 0);
    const float* __restrict__ src = isTxt ? txt : img;
    ushort_t* __restrict__ dst = isTxt ? txtb : imgb;
    float* __restrict__ sq = isTxt ? txt_sq : img_sq;

    const int t = threadIdx.x;                       // 256 thr * float4 = 1024
    const float4 v = reinterpret_cast<const float4*>(src + (size_t)row * DSZ)[t];

    ushort4 o;
    o.x = f2bf_rne(v.x); o.y = f2bf_rne(v.y);
    o.z = f2bf_rne(v.z); o.w = f2bf_rne(v.w);
    reinterpret_cast<ushort4*>(dst + (size_t)row * DSZ)[t] = o;

    float s = v.x * v.x + v.y * v.y + v.z * v.z + v.w * v.w;
    #pragma unroll
    for (int off = 32; off; off >>= 1) s += __shfl_down(s, off);

    __shared__ float lds[4];
    if ((t & 63) == 0) lds[t >> 6] = s;
    __syncthreads();
    if (t == 0) {
        sq[row] = lds[0] + lds[1] + lds[2] + lds[3];
        if (!isTxt) rowsum[row] = 0.0f;   // replaces hipMemsetAsync
    }
}

// ---------------------------------------------------------------------------
// Kernel 2: m97-structure bf16 MFMA cross-GEMM fused with dist/exp/row-sum.
// 128x128 tile / block, 4 waves (2x2), each wave 4x4 frags of 16x16x32.
// A/B staged global->LDS via global_load_lds (16B), double-buffered.
// LDS stays LINEAR; bank-conflict fix is source-side pre-swizzle + swizzled
// read (rule #21): 16B-chunk  chunk' = chunk ^ ((row>>1)&3)  (involution).
// C/D frag mapping: col = lane&15, row = (lane>>4)*4 + j   [verified m89]
// ---------------------------------------------------------------------------
__global__ __launch_bounds__(256) void fused_mfma_kernel(
        const ushort_t* __restrict__ imgb,
        const ushort_t* __restrict__ txtb,
        const float* __restrict__ img_sq, const float* __restrict__ txt_sq,
        float* __restrict__ rowsum, float* __restrict__ diag_dist) {

    __shared__ ushort_t As[2][128 * BK];   // 8 KB per buffer
    __shared__ ushort_t Bs[2][128 * BK];

    const int bi = blockIdx.y;               // image tile
    const int bj = blockIdx.x;               // text tile
    const int tid  = threadIdx.x;
    const int lane = tid & 63;
    const int w    = tid >> 6;               // wave 0..3
    const int wy   = w >> 1, wx = w & 1;
    const int lr   = lane >> 4;              // 0..3  (k-chunk)
    const int lc   = lane & 15;              // 0..15 (row/col within frag)
    const int swz  = (lc >> 1) & 3;          // read-side swizzle term

    const int ib0 = bi * 128;                // block's first image row
    const int jb0 = bj * 128;                // block's first text row
    const int ib  = ib0 + wy * 64;           // wave's first image row
    const int jb  = jb0 + wx * 64;           // wave's first text row

    // staging geometry: chunk q (1 KB) covers tile rows q*16 .. q*16+15;
    // lane l writes LDS byte q*1024 + l*16  <-> (row = q*16 + (l>>2), piece l&3)
    const int srow0 = lane >> 2;             // row offset within 16-row chunk
    const int spiece = lane & 3;

    f32x4 acc[4][4] = {};

    auto stage = [&](int buf, int t) {
        const int k0 = t * BK;
        #pragma unroll
        for (int c = 0; c < 2; ++c) {
            const int q   = w * 2 + c;                    // wave-uniform chunk id
            const int row = q * 16 + srow0;               // tile row this lane feeds
            const int chunk = spiece ^ ((row >> 1) & 3);  // pre-swizzled source piece
            const ushort_t* ga = imgb + (size_t)(ib0 + row) * DSZ + k0 + chunk * 8;
            const ushort_t* gb = txtb + (size_t)(jb0 + row) * DSZ + k0 + chunk * 8;
            __builtin_amdgcn_global_load_lds(
                (const __attribute__((address_space(1))) void*)ga,
                (__attribute__((address_space(3))) void*)&As[buf][q * 512], 16, 0, 0);
            __builtin_amdgcn_global_load_lds(
                (const __attribute__((address_space(1))) void*)gb,
                (__attribute__((address_space(3))) void*)&Bs[buf][q * 512], 16, 0, 0);
        }
    };

    stage(0, 0);
    __syncthreads();                          // drains vmcnt -> buf0 ready
    int cur = 0;

    for (int t = 0; t < NT; ++t) {
        if (t + 1 < NT) stage(cur ^ 1, t + 1);   // prefetch next k-tile

        bf16x8 a[4], b[4];
        const int rsw = (lr ^ swz) * 8;       // swizzled 16B piece within row
        #pragma unroll
        for (int m = 0; m < 4; ++m)
            a[m] = *reinterpret_cast<const bf16x8*>(
                       &As[cur][(wy * 64 + m * 16 + lc) * BK + rsw]);
        #pragma unroll
        for (int n = 0; n < 4; ++n)
            b[n] = *reinterpret_cast<const bf16x8*>(
                       &Bs[cur][(wx * 64 + n * 16 + lc) * BK + rsw]);

        #pragma unroll
        for (int m = 0; m < 4; ++m)
            #pragma unroll
            for (int n = 0; n < 4; ++n)
                acc[m][n] = __builtin_amdgcn_mfma_f32_16x16x32_bf16(
                                a[m], b[n], acc[m][n], 0, 0, 0);

        __syncthreads();                      // next buffer staged; cur reusable
        cur ^= 1;
    }

    // ---- epilogue: dist -> sim -> row partial sums + diagonal ----
    float tq[4];
    #pragma unroll
    for (int n = 0; n < 4; ++n) tq[n] = txt_sq[jb + n * 16 + lc];

    float rs[4][4];                           // [m][j] row partial sums
    #pragma unroll
    for (int m = 0; m < 4; ++m) {
        #pragma unroll
        for (int j = 0; j < 4; ++j) {
            const int gi = ib + m * 16 + lr * 4 + j;
            const float iqv = img_sq[gi];
            float s = 0.0f;
            #pragma unroll
            for (int n = 0; n < 4; ++n) {
                const float d2 = iqv + tq[n] - 2.0f * acc[m][n][j];
                const float d  = sqrtf(fmaxf(d2, 0.0f));
                const float sim = __expf(-20.0f * d);
                s += sim;
                const int gj = jb + n * 16 + lc;
                if (gi == gj) diag_dist[gi] = d;
            }
            rs[m][j] = s;
        }
    }

    #pragma unroll
    for (int off = 1; off < 16; off <<= 1)
        #pragma unroll
        for (int m = 0; m < 4; ++m)
            #pragma unroll
            for (int j = 0; j < 4; ++j)
                rs[m][j] += __shfl_xor(rs[m][j], off);

    if (lc == 0) {
        #pragma unroll
        for (int m = 0; m < 4; ++m)
            #pragma unroll
            for (int j = 0; j < 4; ++j)
                atomicAdd(&rowsum[ib + m * 16 + lr * 4 + j], rs[m][j]);
    }
}

// ---------------------------------------------------------------------------
// Kernel 3: per_sample = d_ii/T + log(rowsum_i - exp(-d_ii/T)); mean over i.
// ---------------------------------------------------------------------------
__global__ __launch_bounds__(256) void finalize_kernel(
        const float* __restrict__ rowsum, const float* __restrict__ diag_dist,
        float* __restrict__ out) {
    const int tid = threadIdx.x;
    float s = 0.0f;
    for (int i = tid; i < BSZ; i += 256) {
        const float d   = diag_dist[i];
        const float num = __expf(-20.0f * d);
        const float den = rowsum[i] - num;
        s += (den != 0.0f) ? (20.0f * d + logf(den)) : 0.0f;
    }
    #pragma unroll
    for (int off = 32; off; off >>= 1) s += __shfl_down(s, off);

    __shared__ float lds[4];
    if ((tid & 63) == 0) lds[tid >> 6] = s;
    __syncthreads();
    if (tid == 0) out[0] = (lds[0] + lds[1] + lds[2] + lds[3]) * (1.0f / (float)BSZ);
}

// ---------------------------------------------------------------------------
extern "C" void kernel_launch(void* const* d_in, const int* in_sizes, int n_in,
                              void* d_out, int out_size, void* d_ws, size_t ws_size,
                              hipStream_t stream) {
    // setup_inputs() order: text_embeddings first, image_embeddings second.
    const float* txt = (const float*)d_in[0];
    const float* img = (const float*)d_in[1];
    float* out = (float*)d_out;

    // workspace layout: bf16 copies (8 MB each) then fp32 scalars
    ushort_t* imgb = (ushort_t*)d_ws;
    ushort_t* txtb = imgb + (size_t)BSZ * DSZ;
    float* fws     = (float*)(txtb + (size_t)BSZ * DSZ);
    float* rowsum  = fws;             // [4096] zeroed inside cvt_norm
    float* diag    = fws + BSZ;       // [4096]
    float* img_sq  = fws + 2 * BSZ;   // [4096]
    float* txt_sq  = fws + 3 * BSZ;   // [4096]

    cvt_norm_kernel<<<dim3(BSZ, 2), 256, 0, stream>>>(img, txt, imgb, txtb,
                                                      img_sq, txt_sq, rowsum);

    fused_mfma_kernel<<<dim3(BSZ / 128, BSZ / 128), 256, 0, stream>>>(
        imgb, txtb, img_sq, txt_sq, rowsum, diag);

    finalize_kernel<<<1, 256, 0, stream>>>(rowsum, diag, out);
}

// Round 5
// 128.984 us; speedup vs baseline: 1.8919x; 1.1894x over previous
//
#include <hip/hip_runtime.h>
#include <hip/hip_bf16.h>
#include <math.h>

#define BSZ 4096
#define DSZ 1024
#define BM  256
#define BN  256
#define BK  64
#define NT  (DSZ / BK)            // 16 K-tiles

typedef unsigned short u16;
typedef __attribute__((ext_vector_type(8))) short bf16x8;   // 8 bf16 = 4 VGPRs
typedef __attribute__((ext_vector_type(4))) float f32x4;    // mfma 16x16 accum

__device__ inline u16 f2bf_rne(float f) {
    unsigned int u = __float_as_uint(f);
    u += 0x7fffu + ((u >> 16) & 1u);      // round-to-nearest-even
    return (u16)(u >> 16);
}

// ---------------------------------------------------------------------------
// Kernel 1: fp32 -> bf16 conversion + exact fp32 row squared-norms.
// Also zeroes rowsum[] (ws is poisoned 0xAA before every launch).
// ---------------------------------------------------------------------------
__global__ __launch_bounds__(256) void cvt_norm_kernel(
        const float* __restrict__ img, const float* __restrict__ txt,
        u16* __restrict__ imgb, u16* __restrict__ txtb,
        float* __restrict__ img_sq, float* __restrict__ txt_sq,
        float* __restrict__ rowsum) {
    const int row = blockIdx.x;
    const bool isTxt = (blockIdx.y != 0);
    const float* __restrict__ src = isTxt ? txt : img;
    u16* __restrict__ dst = isTxt ? txtb : imgb;
    float* __restrict__ sq = isTxt ? txt_sq : img_sq;

    const int t = threadIdx.x;                       // 256 thr * float4 = 1024
    const float4 v = reinterpret_cast<const float4*>(src + (size_t)row * DSZ)[t];

    ushort4 o;
    o.x = f2bf_rne(v.x); o.y = f2bf_rne(v.y);
    o.z = f2bf_rne(v.z); o.w = f2bf_rne(v.w);
    reinterpret_cast<ushort4*>(dst + (size_t)row * DSZ)[t] = o;

    float s = v.x * v.x + v.y * v.y + v.z * v.z + v.w * v.w;
    #pragma unroll
    for (int off = 32; off; off >>= 1) s += __shfl_down(s, off);

    __shared__ float lds[4];
    if ((t & 63) == 0) lds[t >> 6] = s;
    __syncthreads();
    if (t == 0) {
        sq[row] = lds[0] + lds[1] + lds[2] + lds[3];
        if (!isTxt) rowsum[row] = 0.0f;
    }
}

// ---------------------------------------------------------------------------
// Kernel 2: 256x256-tile bf16 MFMA cross-GEMM, phase-split schedule, fused
// dist/exp/row-sum epilogue. 512 threads = 8 waves (2M x 4N); per-wave output
// 128x64 = acc[8][4] frags of 16x16x32. 1 block/CU (grid 16x16 = 256).
//
// LDS (dynamic, 128 KB): A[buf2][half2][128 rows][8 chunks of 16B] then B.
// Bank swizzle (T2 recipe): stored chunk = global chunk ^ (row & 7)
// (involution; applied on the pre-swizzled GLOBAL source per rule #21 since
// global_load_lds writes linearly). Read side applies the same XOR.
//
// Schedule per K-tile (buffer cur), 4 phases:
//   p0: read B-frags(8) + A-frags(4) | issue stage A(next KT, 4 loads) | barrier
//       | setprio(1) 16 MFMA setprio(0) | barrier
//   p1: read A(4) | issue stage B(next, 4 loads) | barrier | 16 MFMA | barrier
//   p2/p3: read A(4) | barrier | 16 MFMA | (p3: __syncthreads = drain)
// Loads issued in p0/p1 have ~2.5 phases of MFMA cover before the end drain.
// Race-freedom: single writer per LDS byte; stage targets buf^1 whose readers
// all passed the previous iteration-end __syncthreads.
// ---------------------------------------------------------------------------
__global__ __launch_bounds__(512, 2) void fused_mfma_kernel(
        const u16* __restrict__ imgb, const u16* __restrict__ txtb,
        const float* __restrict__ img_sq, const float* __restrict__ txt_sq,
        float* __restrict__ rowsum, float* __restrict__ diag_dist) {

    extern __shared__ char smem[];           // 131072 bytes
    // A at 0, B at 65536; each: [buf][half][row 0..127][chunk 0..7] * 16 B

    const int bi = blockIdx.y;               // image tile (rows)
    const int bj = blockIdx.x;               // text tile (cols)
    const int tid  = threadIdx.x;
    const int lane = tid & 63;
    const int w    = tid >> 6;               // wave 0..7
    const int wr   = w >> 2;                 // 0..1  M-half
    const int wc   = w & 3;                  // 0..3  N-quarter
    const int lr   = lane >> 4;              // 0..3  k-chunk within frag
    const int lc   = lane & 15;              // row/col within frag
    const int swz  = lc & 7;                 // row&7 == lc&7 (rows are m*16+lc)

    const int ib0 = bi * BM;
    const int jb0 = bj * BN;

    // staging mapping: within one 8 KB stripe, thread t covers
    // LDS byte t*16  <->  (row = t>>3, chunk = t&7)
    const int srow = tid >> 3;               // 0..63 row within stripe
    const int sch  = tid & 7;

    f32x4 acc[8][4] = {};

    auto stage8k = [&](const u16* __restrict__ src, int xoff, int b, int h,
                       int j, int rowbase, int kt) {
        const int row_h = j * 64 + srow;                 // 0..127 within half
        const int gch   = sch ^ (row_h & 7);             // pre-swizzled source
        const u16* g = src + (size_t)(rowbase + h * 128 + row_h) * DSZ
                           + kt * BK + gch * 8;
        char* dst = smem + xoff + b * 32768 + h * 16384 + j * 8192 + w * 1024;
        __builtin_amdgcn_global_load_lds(
            (const __attribute__((address_space(1))) void*)g,
            (__attribute__((address_space(3))) void*)dst, 16, 0, 0);
    };
    auto stageA = [&](int b, int kt) {
        stage8k(imgb, 0, b, 0, 0, ib0, kt);
        stage8k(imgb, 0, b, 0, 1, ib0, kt);
        stage8k(imgb, 0, b, 1, 0, ib0, kt);
        stage8k(imgb, 0, b, 1, 1, ib0, kt);
    };
    auto stageB = [&](int b, int kt) {
        stage8k(txtb, 65536, b, 0, 0, jb0, kt);
        stage8k(txtb, 65536, b, 0, 1, jb0, kt);
        stage8k(txtb, 65536, b, 1, 0, jb0, kt);
        stage8k(txtb, 65536, b, 1, 1, jb0, kt);
    };

    const char* Abase = smem + wr * 16384;                 // wave's fixed A-half
    const char* Bbase = smem + 65536 + (wc >> 1) * 16384;  // wave's fixed B-half
    const int rboff = (wc & 1) * 64;                       // B row offset in half

    stageA(0, 0);
    stageB(0, 0);
    __syncthreads();

    int cur = 0;
    for (int kt = 0; kt < NT; ++kt) {
        const int nxt = cur ^ 1;
        bf16x8 bfr[2][4];                    // [kk][n], read once in phase 0

        #pragma unroll
        for (int p = 0; p < 4; ++p) {
            bf16x8 afr[2][2];                // [dm][kk]
            if (p == 0) {
                #pragma unroll
                for (int kk = 0; kk < 2; ++kk)
                    #pragma unroll
                    for (int n = 0; n < 4; ++n) {
                        const int rb = rboff + n * 16 + lc;
                        bfr[kk][n] = *reinterpret_cast<const bf16x8*>(
                            Bbase + cur * 32768 + rb * 128
                                  + (((kk * 4 + lr) ^ swz) * 16));
                    }
            }
            #pragma unroll
            for (int dm = 0; dm < 2; ++dm)
                #pragma unroll
                for (int kk = 0; kk < 2; ++kk) {
                    const int ra = (p * 2 + dm) * 16 + lc;
                    afr[dm][kk] = *reinterpret_cast<const bf16x8*>(
                        Abase + cur * 32768 + ra * 128
                              + (((kk * 4 + lr) ^ swz) * 16));
                }

            if (kt + 1 < NT) {               // issue next-tile loads early
                if (p == 0) stageA(nxt, kt + 1);
                else if (p == 1) stageB(nxt, kt + 1);
            }

            __builtin_amdgcn_s_barrier();    // phase-lock before MFMA cluster
            __builtin_amdgcn_s_setprio(1);
            #pragma unroll
            for (int dm = 0; dm < 2; ++dm)
                #pragma unroll
                for (int n = 0; n < 4; ++n)
                    #pragma unroll
                    for (int kk = 0; kk < 2; ++kk)
                        acc[p * 2 + dm][n] = __builtin_amdgcn_mfma_f32_16x16x32_bf16(
                            afr[dm][kk], bfr[kk][n], acc[p * 2 + dm][n], 0, 0, 0);
            __builtin_amdgcn_s_setprio(0);
            if (p < 3) __builtin_amdgcn_s_barrier();
        }
        __syncthreads();                     // drain: next buffer staged+visible
        cur = nxt;
    }

    // ---- epilogue: dist -> sim -> row partial sums + diagonal ----
    const int jw = jb0 + wc * 64;            // wave's first text col
    const int iw = ib0 + wr * 128;           // wave's first image row

    float tq[4];
    #pragma unroll
    for (int n = 0; n < 4; ++n) tq[n] = txt_sq[jw + n * 16 + lc];

    float rs[8][4];
    #pragma unroll
    for (int m = 0; m < 8; ++m) {
        #pragma unroll
        for (int j = 0; j < 4; ++j) {
            const int gi = iw + m * 16 + lr * 4 + j;
            const float iq = img_sq[gi];
            float s = 0.0f;
            #pragma unroll
            for (int n = 0; n < 4; ++n) {
                const float d2 = iq + tq[n] - 2.0f * acc[m][n][j];
                const float d  = sqrtf(fmaxf(d2, 0.0f));
                const float sim = __expf(-20.0f * d);
                s += sim;
                if (gi == jw + n * 16 + lc) diag_dist[gi] = d;
            }
            rs[m][j] = s;
        }
    }

    #pragma unroll
    for (int off = 1; off < 16; off <<= 1)
        #pragma unroll
        for (int m = 0; m < 8; ++m)
            #pragma unroll
            for (int j = 0; j < 4; ++j)
                rs[m][j] += __shfl_xor(rs[m][j], off);

    if (lc == 0) {
        #pragma unroll
        for (int m = 0; m < 8; ++m)
            #pragma unroll
            for (int j = 0; j < 4; ++j)
                atomicAdd(&rowsum[iw + m * 16 + lr * 4 + j], rs[m][j]);
    }
}

// ---------------------------------------------------------------------------
// Kernel 3: per_sample = d_ii/T + log(rowsum_i - exp(-d_ii/T)); mean over i.
// ---------------------------------------------------------------------------
__global__ __launch_bounds__(256) void finalize_kernel(
        const float* __restrict__ rowsum, const float* __restrict__ diag_dist,
        float* __restrict__ out) {
    const int tid = threadIdx.x;
    float s = 0.0f;
    for (int i = tid; i < BSZ; i += 256) {
        const float d   = diag_dist[i];
        const float num = __expf(-20.0f * d);
        const float den = rowsum[i] - num;
        s += (den != 0.0f) ? (20.0f * d + logf(den)) : 0.0f;
    }
    #pragma unroll
    for (int off = 32; off; off >>= 1) s += __shfl_down(s, off);

    __shared__ float lds[4];
    if ((tid & 63) == 0) lds[tid >> 6] = s;
    __syncthreads();
    if (tid == 0) out[0] = (lds[0] + lds[1] + lds[2] + lds[3]) * (1.0f / (float)BSZ);
}

// ---------------------------------------------------------------------------
extern "C" void kernel_launch(void* const* d_in, const int* in_sizes, int n_in,
                              void* d_out, int out_size, void* d_ws, size_t ws_size,
                              hipStream_t stream) {
    // setup_inputs() order: text_embeddings first, image_embeddings second.
    const float* txt = (const float*)d_in[0];
    const float* img = (const float*)d_in[1];
    float* out = (float*)d_out;

    u16* imgb = (u16*)d_ws;
    u16* txtb = imgb + (size_t)BSZ * DSZ;
    float* fws     = (float*)(txtb + (size_t)BSZ * DSZ);
    float* rowsum  = fws;             // [4096] zeroed inside cvt_norm
    float* diag    = fws + BSZ;       // [4096]
    float* img_sq  = fws + 2 * BSZ;   // [4096]
    float* txt_sq  = fws + 3 * BSZ;   // [4096]

    // opt in to 128 KB dynamic LDS (device-global config, graph-capture safe)
    (void)hipFuncSetAttribute((const void*)fused_mfma_kernel,
                              hipFuncAttributeMaxDynamicSharedMemorySize, 131072);

    cvt_norm_kernel<<<dim3(BSZ, 2), 256, 0, stream>>>(img, txt, imgb, txtb,
                                                      img_sq, txt_sq, rowsum);

    fused_mfma_kernel<<<dim3(BSZ / BN, BSZ / BM), 512, 131072, stream>>>(
        imgb, txtb, img_sq, txt_sq, rowsum, diag);

    finalize_kernel<<<1, 256, 0, stream>>>(rowsum, diag, out);
}

// Round 6
// 127.836 us; speedup vs baseline: 1.9089x; 1.0090x over previous
//
#include <hip/hip_runtime.h>
#include <hip/hip_bf16.h>
#include <math.h>

#define BSZ 4096
#define DSZ 1024
#define BM  256
#define BN  256
#define BK  64
#define NT  16          // K-tiles
#define NIT 8           // iterations, 2 K-tiles each

typedef unsigned short u16;
typedef __attribute__((ext_vector_type(8))) short bf16x8;   // 8 bf16 = 4 VGPRs
typedef __attribute__((ext_vector_type(4))) float f32x4;    // mfma 16x16 accum

__device__ inline u16 f2bf_rne(float f) {
    unsigned int u = __float_as_uint(f);
    u += 0x7fffu + ((u >> 16) & 1u);      // round-to-nearest-even
    return (u16)(u >> 16);
}

// ---------------------------------------------------------------------------
// Kernel 1: fp32 -> bf16 conversion + exact fp32 row squared-norms.
// Also zeroes rowsum[] (ws is poisoned 0xAA before every launch).
// ---------------------------------------------------------------------------
__global__ __launch_bounds__(256) void cvt_norm_kernel(
        const float* __restrict__ img, const float* __restrict__ txt,
        u16* __restrict__ imgb, u16* __restrict__ txtb,
        float* __restrict__ img_sq, float* __restrict__ txt_sq,
        float* __restrict__ rowsum) {
    const int row = blockIdx.x;
    const bool isTxt = (blockIdx.y != 0);
    const float* __restrict__ src = isTxt ? txt : img;
    u16* __restrict__ dst = isTxt ? txtb : imgb;
    float* __restrict__ sq = isTxt ? txt_sq : img_sq;

    const int t = threadIdx.x;                       // 256 thr * float4 = 1024
    const float4 v = reinterpret_cast<const float4*>(src + (size_t)row * DSZ)[t];

    ushort4 o;
    o.x = f2bf_rne(v.x); o.y = f2bf_rne(v.y);
    o.z = f2bf_rne(v.z); o.w = f2bf_rne(v.w);
    reinterpret_cast<ushort4*>(dst + (size_t)row * DSZ)[t] = o;

    float s = v.x * v.x + v.y * v.y + v.z * v.z + v.w * v.w;
    #pragma unroll
    for (int off = 32; off; off >>= 1) s += __shfl_down(s, off);

    __shared__ float lds[4];
    if ((t & 63) == 0) lds[t >> 6] = s;
    __syncthreads();
    if (t == 0) {
        sq[row] = lds[0] + lds[1] + lds[2] + lds[3];
        if (!isTxt) rowsum[row] = 0.0f;
    }
}

// ---------------------------------------------------------------------------
// Kernel 2: 256x256 bf16 MFMA cross-GEMM, m201-style 8-phase counted-vmcnt
// schedule, fused dist/exp/row-sum epilogue. 512 thr = 8 waves (2M x 4N);
// per-wave 128x64 output = acc[8][4]. Grid 16x16 = 1 block/CU.
//
// LDS 128 KB: A[buf2][half2][128 rows][8 chunks x 16B] @0, B same @65536.
// Tile parity == buffer parity (tiles/iter = {2i, 2i+1}) -> static offsets.
// Swizzle (T2, rule #21): stored chunk s holds global chunk s^(row&7)
// (pre-swizzled source; LDS linear); read XORs the same -> 0 bank conflicts
// and correct k-chunk (XOR cancels). Verified R5: absmax 0, conflicts 0.
//
// Stage schedule (1 half-tile = 2 loads/thread per phase), iteration i:
//   ph0: A.h0(2i+1)  ph1: A.h1(2i+1)   [slot freed by iter i-1 ph7 reads]
//   ph2: B.h0(2i+2)  ph3: B.h1(2i+2)   [B(2i) last read at ph0]
//   ph4: A.h0(2i+2)  ph5: A.h1(2i+2)   [A(2i) last read at ph3]
//   ph6: B.h0(2i+3)  ph7: B.h1(2i+3)   [B(2i+1) last read at ph4]
// Guards: vmcnt(4) at end of ph3 (t1's 4 half-tiles drained, 2 newest remain)
// and end of ph7 (t0' drained). Last iter: vmcnt(0) at ph3. Loads thus stay
// in flight across ~4 MFMA phases (T4) instead of draining per tile.
// ---------------------------------------------------------------------------
__global__ __launch_bounds__(512, 2) void fused_mfma_kernel(
        const u16* __restrict__ imgb, const u16* __restrict__ txtb,
        const float* __restrict__ img_sq, const float* __restrict__ txt_sq,
        float* __restrict__ rowsum, float* __restrict__ diag_dist) {

    extern __shared__ char smem[];           // 131072 bytes

    const int lin = blockIdx.y * 16 + blockIdx.x;
    const int sw  = (lin & 7) * 32 + (lin >> 3);   // bijective XCD swizzle
    const int bi = sw >> 4, bj = sw & 15;

    const int tid  = threadIdx.x;
    const int lane = tid & 63;
    const int w    = tid >> 6;               // wave 0..7
    const int wr   = w >> 2;                 // 0..1  M-half
    const int wc   = w & 3;                  // 0..3  N-quarter
    const int lr   = lane >> 4;              // 0..3
    const int lc   = lane & 15;
    const int swz  = lc & 7;                 // == row&7 for rows m*16+lc

    const int ib0 = bi * BM;
    const int jb0 = bj * BN;

    auto stageHT = [&](int mat, int kt, int h) {   // one half-tile: 2 loads/thr
        const u16* base   = mat ? txtb : imgb;
        const int rowbase = mat ? jb0 : ib0;
        const int xoff    = mat ? 65536 : 0;
        const int b = kt & 1;
        #pragma unroll
        for (int j = 0; j < 2; ++j) {
            const int row_h = j * 64 + (tid >> 3);        // 0..127 within half
            const int gch   = (tid & 7) ^ (row_h & 7);    // pre-swizzled src
            const u16* g = base + (size_t)(rowbase + h * 128 + row_h) * DSZ
                                + kt * BK + gch * 8;
            char* dst = smem + xoff + b * 32768 + h * 16384 + j * 8192 + w * 1024;
            __builtin_amdgcn_global_load_lds(
                (const __attribute__((address_space(1))) void*)g,
                (__attribute__((address_space(3))) void*)dst, 16, 0, 0);
        }
    };

    // prologue: tile0 fully + tile1's B halves (12 loads/thread... 6 half-tiles)
    stageHT(0, 0, 0); stageHT(0, 0, 1);
    stageHT(1, 0, 0); stageHT(1, 0, 1);
    stageHT(1, 1, 0); stageHT(1, 1, 1);
    asm volatile("s_waitcnt vmcnt(4)" ::: "memory");   // tile0's 8 loads done
    __builtin_amdgcn_s_barrier();

    f32x4 acc[8][4] = {};
    bf16x8 bfr[2][4];

    const char* Ab[2] = { smem + wr * 16384,
                          smem + 32768 + wr * 16384 };
    const char* Bb[2] = { smem + 65536 + (wc >> 1) * 16384,
                          smem + 65536 + 32768 + (wc >> 1) * 16384 };
    const int rboff = (wc & 1) * 64;

    for (int i = 0; i < NIT; ++i) {
        const bool more = (i < NIT - 1);
        #pragma unroll
        for (int p = 0; p < 8; ++p) {
            const int tsel = p >> 2;         // which K-tile of the pair
            const int q    = p & 3;          // quadrant (m-pair)

            // ---- ds_reads for this phase ----
            if (q == 0) {
                #pragma unroll
                for (int kk = 0; kk < 2; ++kk)
                    #pragma unroll
                    for (int n = 0; n < 4; ++n)
                        bfr[kk][n] = *reinterpret_cast<const bf16x8*>(
                            Bb[tsel] + (rboff + n * 16 + lc) * 128
                                     + (((kk * 4 + lr) ^ swz) * 16));
            }
            bf16x8 afr[2][2];
            #pragma unroll
            for (int dm = 0; dm < 2; ++dm)
                #pragma unroll
                for (int kk = 0; kk < 2; ++kk)
                    afr[dm][kk] = *reinterpret_cast<const bf16x8*>(
                        Ab[tsel] + ((q * 2 + dm) * 16 + lc) * 128
                                 + (((kk * 4 + lr) ^ swz) * 16));

            // ---- stage one half-tile (sliding schedule) ----
            if (p == 0)      stageHT(0, 2 * i + 1, 0);
            else if (p == 1) stageHT(0, 2 * i + 1, 1);
            else if (p == 2) { if (more) stageHT(1, 2 * i + 2, 0); }
            else if (p == 3) { if (more) stageHT(1, 2 * i + 2, 1); }
            else if (p == 4) { if (more) stageHT(0, 2 * i + 2, 0); }
            else if (p == 5) { if (more) stageHT(0, 2 * i + 2, 1); }
            else if (p == 6) { if (more) stageHT(1, 2 * i + 3, 0); }
            else             { if (more) stageHT(1, 2 * i + 3, 1); }

            __builtin_amdgcn_s_barrier();
            asm volatile("s_waitcnt lgkmcnt(0)" ::: "memory");
            __builtin_amdgcn_sched_barrier(0);          // rule #18

            __builtin_amdgcn_s_setprio(1);
            #pragma unroll
            for (int dm = 0; dm < 2; ++dm)
                #pragma unroll
                for (int n = 0; n < 4; ++n)
                    #pragma unroll
                    for (int kk = 0; kk < 2; ++kk)
                        acc[q * 2 + dm][n] = __builtin_amdgcn_mfma_f32_16x16x32_bf16(
                            afr[dm][kk], bfr[kk][n], acc[q * 2 + dm][n], 0, 0, 0);
            __builtin_amdgcn_s_setprio(0);

            // ---- counted guards (T4): never 0 in steady state ----
            if (p == 3) {
                if (more) asm volatile("s_waitcnt vmcnt(4)" ::: "memory");
                else      asm volatile("s_waitcnt vmcnt(0)" ::: "memory");
            } else if (p == 7) {
                if (more) asm volatile("s_waitcnt vmcnt(4)" ::: "memory");
            }
            __builtin_amdgcn_s_barrier();
        }
    }

    // ---- epilogue: dist -> sim -> row partial sums + diagonal ----
    const int jw = jb0 + wc * 64;            // wave's first text col
    const int iw = ib0 + wr * 128;           // wave's first image row

    float tq[4];
    #pragma unroll
    for (int n = 0; n < 4; ++n) tq[n] = txt_sq[jw + n * 16 + lc];

    float rs[8][4];
    #pragma unroll
    for (int m = 0; m < 8; ++m) {
        #pragma unroll
        for (int j = 0; j < 4; ++j) {
            const int gi = iw + m * 16 + lr * 4 + j;
            const float iq = img_sq[gi];
            float s = 0.0f;
            #pragma unroll
            for (int n = 0; n < 4; ++n) {
                const float d2 = iq + tq[n] - 2.0f * acc[m][n][j];
                const float d  = sqrtf(fmaxf(d2, 0.0f));
                const float sim = __expf(-20.0f * d);
                s += sim;
                if (gi == jw + n * 16 + lc) diag_dist[gi] = d;
            }
            rs[m][j] = s;
        }
    }

    #pragma unroll
    for (int off = 1; off < 16; off <<= 1)
        #pragma unroll
        for (int m = 0; m < 8; ++m)
            #pragma unroll
            for (int j = 0; j < 4; ++j)
                rs[m][j] += __shfl_xor(rs[m][j], off);

    if (lc == 0) {
        #pragma unroll
        for (int m = 0; m < 8; ++m)
            #pragma unroll
            for (int j = 0; j < 4; ++j)
                atomicAdd(&rowsum[iw + m * 16 + lr * 4 + j], rs[m][j]);
    }
}

// ---------------------------------------------------------------------------
// Kernel 3: per_sample = d_ii/T + log(rowsum_i - exp(-d_ii/T)); mean over i.
// ---------------------------------------------------------------------------
__global__ __launch_bounds__(256) void finalize_kernel(
        const float* __restrict__ rowsum, const float* __restrict__ diag_dist,
        float* __restrict__ out) {
    const int tid = threadIdx.x;
    float s = 0.0f;
    for (int i = tid; i < BSZ; i += 256) {
        const float d   = diag_dist[i];
        const float num = __expf(-20.0f * d);
        const float den = rowsum[i] - num;
        s += (den != 0.0f) ? (20.0f * d + logf(den)) : 0.0f;
    }
    #pragma unroll
    for (int off = 32; off; off >>= 1) s += __shfl_down(s, off);

    __shared__ float lds[4];
    if ((tid & 63) == 0) lds[tid >> 6] = s;
    __syncthreads();
    if (tid == 0) out[0] = (lds[0] + lds[1] + lds[2] + lds[3]) * (1.0f / (float)BSZ);
}

// ---------------------------------------------------------------------------
extern "C" void kernel_launch(void* const* d_in, const int* in_sizes, int n_in,
                              void* d_out, int out_size, void* d_ws, size_t ws_size,
                              hipStream_t stream) {
    // setup_inputs() order: text_embeddings first, image_embeddings second.
    const float* txt = (const float*)d_in[0];
    const float* img = (const float*)d_in[1];
    float* out = (float*)d_out;

    u16* imgb = (u16*)d_ws;
    u16* txtb = imgb + (size_t)BSZ * DSZ;
    float* fws     = (float*)(txtb + (size_t)BSZ * DSZ);
    float* rowsum  = fws;             // [4096] zeroed inside cvt_norm
    float* diag    = fws + BSZ;       // [4096]
    float* img_sq  = fws + 2 * BSZ;   // [4096]
    float* txt_sq  = fws + 3 * BSZ;   // [4096]

    (void)hipFuncSetAttribute((const void*)fused_mfma_kernel,
                              hipFuncAttributeMaxDynamicSharedMemorySize, 131072);

    cvt_norm_kernel<<<dim3(BSZ, 2), 256, 0, stream>>>(img, txt, imgb, txtb,
                                                      img_sq, txt_sq, rowsum);

    fused_mfma_kernel<<<dim3(BSZ / BN, BSZ / BM), 512, 131072, stream>>>(
        imgb, txtb, img_sq, txt_sq, rowsum, diag);

    finalize_kernel<<<1, 256, 0, stream>>>(rowsum, diag, out);
}